// Round 2
// baseline (10658.955 us; speedup 1.0000x reference)
//
#include <hip/hip_runtime.h>
#include <hip/hip_bf16.h>

#define SEQ 4096
#define EMB 1024
#define HID 2048
#define G4  8192
#define NL  256

typedef __attribute__((ext_vector_type(8))) short bf16x8;
typedef __attribute__((ext_vector_type(4))) float f32x4;

static __device__ __forceinline__ unsigned short f2bf(float f) {
    unsigned int x = __builtin_bit_cast(unsigned int, f);
    return (unsigned short)((x + 0x7FFFu + ((x >> 16) & 1u)) >> 16);
}
static __device__ __forceinline__ float bf2f(unsigned short u) {
    return __builtin_bit_cast(float, ((unsigned int)u) << 16);
}
static __device__ __forceinline__ unsigned long long aload(const unsigned long long* p) {
    return __hip_atomic_load(p, __ATOMIC_RELAXED, __HIP_MEMORY_SCOPE_AGENT);
}
static __device__ __forceinline__ float frcp(float x) {
    return __builtin_amdgcn_rcpf(x);
}
static __device__ __forceinline__ float fsigm(float x) {
    return frcp(1.f + __expf(-x));
}
static __device__ __forceinline__ float ftanh(float x) {
    return 1.f - 2.f * frcp(__expf(2.f * x) + 1.f);
}

// ---------------- fp32 -> bf16 convert ----------------
__global__ __launch_bounds__(256) void k_f2b(const float* __restrict__ in,
                                             unsigned short* __restrict__ out, int n) {
    int i = (blockIdx.x * 256 + threadIdx.x) * 4;
    if (i < n) {
        float4 v = *(const float4*)&in[i];
        ushort4 u;
        u.x = f2bf(v.x); u.y = f2bf(v.y); u.z = f2bf(v.z); u.w = f2bf(v.w);
        *(ushort4*)&out[i] = u;
    }
}

// ---------------- embedding gather + cast ----------------
__global__ __launch_bounds__(256) void k_emb(const int* __restrict__ ids,
                                             const float* __restrict__ W_emb,
                                             unsigned short* __restrict__ out) {
    int t = blockIdx.x;
    int e0 = threadIdx.x * 4;
    const float4 v = *(const float4*)&W_emb[(size_t)ids[t] * EMB + e0];
    ushort4 u;
    u.x = f2bf(v.x); u.y = f2bf(v.y); u.z = f2bf(v.z); u.w = f2bf(v.w);
    *(ushort4*)&out[(size_t)t * EMB + e0] = u;
}

// ---------------- bf16 MFMA GEMM:  C[M,N] = A[M,K] * B[N,K]^T + bias ----------------
// Cb path is used ONLY for the xg precompute (N==G4): stores are swizzled to
// [t][unit][gate] layout (u*4+q) so k_lstm's per-step prefetch is one 8B load.
#define BM 128
#define BN 128
#define BK 32
__global__ __launch_bounds__(256) void k_gemm_bt(
    const unsigned short* __restrict__ A, const unsigned short* __restrict__ B,
    const float* __restrict__ bias1, const float* __restrict__ bias2,
    float* __restrict__ Cf, unsigned short* __restrict__ Cb,
    int M, int N, int K)
{
    __shared__ unsigned short As[BM * BK];
    __shared__ unsigned short Bs[BN * BK];
    const int bm = blockIdx.x * BM;
    const int bn = blockIdx.y * BN;
    const int tid = threadIdx.x;
    const int wave = tid >> 6, lane = tid & 63;
    const int wm = (wave & 1) * 64, wn = (wave >> 1) * 64;
    const int row16 = lane & 15, quad = lane >> 4;

    f32x4 acc[4][4];
#pragma unroll
    for (int i = 0; i < 4; ++i)
#pragma unroll
        for (int j = 0; j < 4; ++j) acc[i][j] = (f32x4){0.f, 0.f, 0.f, 0.f};

    for (int k0 = 0; k0 < K; k0 += BK) {
        __syncthreads();
#pragma unroll
        for (int s = 0; s < 2; ++s) {
            int c = tid + s * 256;
            int r = c >> 2, col = (c & 3) * 8;
            *(uint4*)&As[r * BK + col] = *(const uint4*)&A[(size_t)(bm + r) * K + k0 + col];
            *(uint4*)&Bs[r * BK + col] = *(const uint4*)&B[(size_t)(bn + r) * K + k0 + col];
        }
        __syncthreads();
        bf16x8 af[4], bfr[4];
#pragma unroll
        for (int i = 0; i < 4; ++i) {
            af[i]  = *(const bf16x8*)&As[(wm + i * 16 + row16) * BK + quad * 8];
            bfr[i] = *(const bf16x8*)&Bs[(wn + i * 16 + row16) * BK + quad * 8];
        }
#pragma unroll
        for (int i = 0; i < 4; ++i)
#pragma unroll
            for (int j = 0; j < 4; ++j)
                acc[i][j] = __builtin_amdgcn_mfma_f32_16x16x32_bf16(af[i], bfr[j], acc[i][j], 0, 0, 0);
    }

#pragma unroll
    for (int j = 0; j < 4; ++j) {
        int col = bn + wn + j * 16 + row16;
        float bsum = (bias1 ? bias1[col] : 0.f) + (bias2 ? bias2[col] : 0.f);
#pragma unroll
        for (int i = 0; i < 4; ++i) {
#pragma unroll
            for (int r = 0; r < 4; ++r) {
                int row = bm + wm + i * 16 + quad * 4 + r;
                float v = acc[i][j][r] + bsum;
                if (Cf) Cf[(size_t)row * N + col] = v;
                else    Cb[(size_t)row * N + ((col & 2047) << 2) + (col >> 11)] = f2bf(v);
            }
        }
    }
}

// ---------------- persistent LSTM recurrence (register-direct MFMA) ----------------
// r2: 128 blocks x 1024 threads, 16 units/block (was 256 x 8). Block b owns
// h[b*16..b*16+16) and gate rows {q*2048 + b*16 + u}, u=sub (16 rows = 1 gate per
// row-group). Wave w owns k-cols [w*128, w*128+128): 16 A-frags (4 gates x 4
// k-chunks) in 64 VGPRs. h exchange: 8-way replicated mailbox of tagged 8B words
// (tag32 | 2xbf16), consumer block b polls replica b&7 (16 consumers/replica).
// r2 theory (from r1 counters): WRITE_SIZE showed publish stores write through
// to HBM (no-allocate) and FETCH_SIZE showed first polls then MISS LLC -> HBM
// (~900cy). Changes:
//   * publish via atomicExch (RMW executes AT the LLC, line stays resident ->
//     polls become LLC hits; HBM mailbox traffic disappears)
//   * 2-deep pipelined poll loads (vmcnt(1)/vmcnt(0)) halve the detect quantum
//   * 128 producers halve the skew pool + per-replica consumer count
//   * v_rcp_f32 in activations (kills fp32 divide sequence in serial section)
#define NBLK 128
#define UPB  16
#define LSTM_LDS 90112
__global__ __launch_bounds__(1024, 1) void k_lstm(
    const unsigned short* __restrict__ Whhb, // [8192,2048] bf16
    const unsigned short* __restrict__ xg,   // [4096][2048 units][4 gates] bf16
    const float* __restrict__ h0, const float* __restrict__ c0,
    unsigned short* __restrict__ hsb,        // [4096,2048] bf16
    float* __restrict__ outHC,               // d_out + SEQ*NL : [hL(2048), cL(2048)]
    unsigned long long* __restrict__ hcomm)  // [2][8 replicas][1024] tagged words
{
    extern __shared__ char smem[];
    float* LDSp = (float*)smem;              // 2 buffers x [64 rows][stride 20]

    const int b = blockIdx.x, tid = threadIdx.x;
    const int wave = tid >> 6, lane = tid & 63;
    const int sub = lane & 15, quad = lane >> 4;

    // A-frags: gate q, row (unit) = sub, k = wave*128 + kc*32 + quad*8 + [0,8)
    bf16x8 afr[4][4];
#pragma unroll
    for (int q = 0; q < 4; ++q) {
        const unsigned short* wp =
            Whhb + ((size_t)(q * HID + b * UPB + sub)) * HID + wave * 128 + quad * 8;
#pragma unroll
        for (int kc = 0; kc < 4; ++kc) afr[q][kc] = *(const bf16x8*)(wp + kc * 32);
    }

    float creg = 0.f;
    if (tid < UPB) creg = c0[b * UPB + tid];

    for (int t = 0; t < SEQ; ++t) {
        // wave0 activation lanes prefetch their 4 x-gate values (one 8B load)
        float xq0 = 0.f, xq1 = 0.f, xq2 = 0.f, xq3 = 0.f;
        if (wave == 0 && lane < UPB) {
            uint2 w2 = *(const uint2*)(xg + (size_t)t * G4 + (size_t)(b * UPB + lane) * 4);
            xq0 = bf2f((unsigned short)(w2.x & 0xffff));
            xq1 = bf2f((unsigned short)(w2.x >> 16));
            xq2 = bf2f((unsigned short)(w2.y & 0xffff));
            xq3 = bf2f((unsigned short)(w2.y >> 16));
        }

        f32x4 acc[4];
#pragma unroll
        for (int q = 0; q < 4; ++q) acc[q] = (f32x4){0.f, 0.f, 0.f, 0.f};

        if (t == 0) {
#pragma unroll
            for (int kc = 0; kc < 4; ++kc) {
                const float* hp = h0 + wave * 128 + kc * 32 + quad * 8;
                float4 va = *(const float4*)hp;
                float4 vb = *(const float4*)(hp + 4);
                uint4 d;
                d.x = (unsigned)f2bf(va.x) | ((unsigned)f2bf(va.y) << 16);
                d.y = (unsigned)f2bf(va.z) | ((unsigned)f2bf(va.w) << 16);
                d.z = (unsigned)f2bf(vb.x) | ((unsigned)f2bf(vb.y) << 16);
                d.w = (unsigned)f2bf(vb.z) | ((unsigned)f2bf(vb.w) << 16);
                bf16x8 hf = __builtin_bit_cast(bf16x8, d);
#pragma unroll
                for (int q = 0; q < 4; ++q)
                    acc[q] = __builtin_amdgcn_mfma_f32_16x16x32_bf16(afr[q][kc], hf, acc[q], 0, 0, 0);
            }
        } else {
            // lane L polls its own word in THIS block's replica (b&7).
            // 2-deep pipelined polls: two relaxed loads in flight -> compiler
            // emits vmcnt(1)/vmcnt(0) pair, halving the detect quantum.
            const unsigned long long* src =
                hcomm + (size_t)((t - 1) & 1) * 8192 + (size_t)(b & 7) * 1024 + wave * 64;
            const unsigned tag = (unsigned)t;
            unsigned long long x = aload(&src[lane]);
            if ((unsigned)(x >> 32) != tag) {
                __builtin_amdgcn_s_sleep(8);
                for (;;) {
                    unsigned long long x1 = aload(&src[lane]);
                    unsigned long long x2 = aload(&src[lane]);
                    if ((unsigned)(x1 >> 32) == tag) { x = x1; break; }
                    if ((unsigned)(x2 >> 32) == tag) { x = x2; break; }
                    __builtin_amdgcn_s_sleep(1);
                }
            }
            int myd = (int)(unsigned)x;
#pragma unroll
            for (int kc = 0; kc < 4; ++kc) {
                const int sl = kc * 16 + quad * 4;
                uint4 d;
                d.x = (unsigned)__shfl(myd, sl + 0);
                d.y = (unsigned)__shfl(myd, sl + 1);
                d.z = (unsigned)__shfl(myd, sl + 2);
                d.w = (unsigned)__shfl(myd, sl + 3);
                bf16x8 hf = __builtin_bit_cast(bf16x8, d);
#pragma unroll
                for (int q = 0; q < 4; ++q)
                    acc[q] = __builtin_amdgcn_mfma_f32_16x16x32_bf16(afr[q][kc], hf, acc[q], 0, 0, 0);
            }
        }

        // partials -> double-buffered LDS, ONE barrier per step.
        // P[row][w], row = q*16 + (unit), stride 20 (16B-aligned, odd-ish banks)
        float* P = LDSp + (t & 1) * 1280;
        if (sub == 0) {
#pragma unroll
            for (int q = 0; q < 4; ++q)
#pragma unroll
                for (int r = 0; r < 4; ++r)
                    P[(q * 16 + quad * 4 + r) * 20 + wave] = acc[q][r];
        }
        __syncthreads();

        if (wave == 0) {
            __builtin_amdgcn_s_setprio(1);
            // lane = q*16 + u : reduce 16 wave-partials for its gate row
            const float* rp = P + lane * 20;
            f32x4 s = *(const f32x4*)rp;
            s += *(const f32x4*)(rp + 4);
            s += *(const f32x4*)(rp + 8);
            s += *(const f32x4*)(rp + 12);
            float g = s[0] + s[1] + s[2] + s[3];
            // unit u (lane<16): gates at lanes u, 16+u, 32+u, 48+u
            float gF = __shfl(g, 16 + (lane & 15));
            float gG = __shfl(g, 32 + (lane & 15));
            float gO = __shfl(g, 48 + (lane & 15));
            unsigned hv = 0;
            float cn = 0.f, hn = 0.f;
            if (lane < UPB) {
                float i_ = fsigm(g + xq0);          // own-lane value first: overlaps shfls
                float f_ = fsigm(gF + xq1);
                float g_ = ftanh(gG + xq2);
                float o_ = fsigm(gO + xq3);
                cn = f_ * creg + i_ * g_;
                hn = o_ * ftanh(cn);
                creg = cn;
                hv = (unsigned)f2bf(hn);
            }
            // publish: word jj=lane&7 packs units 2jj,2jj+1 ; replica = lane>>3.
            // atomicExch => RMW at LLC => line stays LLC-resident for pollers.
            {
                int jj = lane & 7;
                unsigned lo = (unsigned)__shfl((int)hv, 2 * jj);
                unsigned hi = (unsigned)__shfl((int)hv, 2 * jj + 1);
                unsigned long long wrd =
                    (((unsigned long long)(unsigned)(t + 1)) << 32)
                    | (unsigned long long)(lo | (hi << 16));
                (void)__hip_atomic_exchange(
                    &hcomm[(size_t)(t & 1) * 8192 + (size_t)(lane >> 3) * 1024 + b * 8 + jj],
                    wrd, __ATOMIC_RELAXED, __HIP_MEMORY_SCOPE_AGENT);
            }
            __builtin_amdgcn_s_setprio(0);
            if (lane < UPB) {
                hsb[(size_t)t * HID + b * UPB + lane] = (unsigned short)hv;
                if (t == SEQ - 1) {
                    outHC[b * UPB + lane] = hn;
                    outHC[HID + b * UPB + lane] = cn;
                }
            }
        }
    }
}

// ---------------- relu + log_softmax over rows of 256 ----------------
__global__ __launch_bounds__(256) void k_softmax(const float* __restrict__ logits,
                                                 float* __restrict__ out) {
    int row = blockIdx.x * 4 + (threadIdx.x >> 6);
    int lane = threadIdx.x & 63;
    const float* Lr = logits + (size_t)row * NL;
    float4 v = *(const float4*)&Lr[lane * 4];
    v.x = fmaxf(v.x, 0.f); v.y = fmaxf(v.y, 0.f);
    v.z = fmaxf(v.z, 0.f); v.w = fmaxf(v.w, 0.f);
    float m = fmaxf(fmaxf(v.x, v.y), fmaxf(v.z, v.w));
#pragma unroll
    for (int off = 32; off > 0; off >>= 1) m = fmaxf(m, __shfl_xor(m, off));
    float e = __expf(v.x - m) + __expf(v.y - m) + __expf(v.z - m) + __expf(v.w - m);
#pragma unroll
    for (int off = 32; off > 0; off >>= 1) e += __shfl_xor(e, off);
    float ls = __logf(e) + m;
    float4 o;
    o.x = v.x - ls; o.y = v.y - ls; o.z = v.z - ls; o.w = v.w - ls;
    *(float4*)&out[(size_t)row * NL + lane * 4] = o;
}

extern "C" void kernel_launch(void* const* d_in, const int* in_sizes, int n_in,
                              void* d_out, int out_size, void* d_ws, size_t ws_size,
                              hipStream_t stream) {
    const int*   ids   = (const int*)d_in[0];
    const float* h0    = (const float*)d_in[1];
    const float* c0    = (const float*)d_in[2];
    const float* W_emb = (const float*)d_in[3];
    const float* W_ih  = (const float*)d_in[4];
    const float* W_hh  = (const float*)d_in[5];
    const float* b_ih  = (const float*)d_in[6];
    const float* b_hh  = (const float*)d_in[7];
    const float* W_out = (const float*)d_in[8];
    const float* b_out = (const float*)d_in[9];
    float* out = (float*)d_out;

    char* ws = (char*)d_ws;
    unsigned short* xg    = (unsigned short*)(ws);                 // 64MB  [4096][2048u][4q] bf16
    unsigned short* hsb   = (unsigned short*)(ws + 67108864);      // 16MB  [4096,2048] bf16
    unsigned short* Wihb  = (unsigned short*)(ws + 83886080);      // 16MB
    unsigned short* embb  = (unsigned short*)(ws + 100663296);     // 8MB
    unsigned short* Woutb = (unsigned short*)(ws + 109051904);     // 1MB
    float*          logit = (float*)(ws + 110100480);              // 4MB
    unsigned short* Whhb  = (unsigned short*)(ws + 114294784);     // 32MB [8192,2048] bf16
    unsigned long long* hcomm = (unsigned long long*)(ws + 147849216); // 128KB (0xAA poison != any tag)

    k_f2b<<<(G4 * EMB / 4 + 255) / 256, 256, 0, stream>>>(W_ih, Wihb, G4 * EMB);
    k_f2b<<<(NL * HID / 4 + 255) / 256, 256, 0, stream>>>(W_out, Woutb, NL * HID);
    k_f2b<<<(G4 * HID / 4 + 255) / 256, 256, 0, stream>>>(W_hh, Whhb, G4 * HID);
    k_emb<<<SEQ, 256, 0, stream>>>(ids, W_emb, embb);

    dim3 g1(SEQ / BM, G4 / BN);
    k_gemm_bt<<<g1, 256, 0, stream>>>(embb, Wihb, b_ih, b_hh, nullptr, xg, SEQ, G4, EMB);

    hipFuncSetAttribute((const void*)k_lstm, hipFuncAttributeMaxDynamicSharedMemorySize, LSTM_LDS);
    k_lstm<<<NBLK, 1024, LSTM_LDS, stream>>>(Whhb, xg, h0, c0, hsb, out + (size_t)SEQ * NL, hcomm);

    dim3 g2(SEQ / BM, NL / BN);
    k_gemm_bt<<<g2, 256, 0, stream>>>(hsb, Woutb, b_out, nullptr, logit, nullptr, SEQ, NL, HID);

    k_softmax<<<SEQ / 4, 256, 0, stream>>>(logit, out);
}